// Round 1
// baseline (187.458 us; speedup 1.0000x reference)
//
#include <hip/hip_runtime.h>
#include <hip/hip_bf16.h>

typedef unsigned short u16;
typedef unsigned int   u32;
typedef short bf16x8 __attribute__((ext_vector_type(8)));
typedef short bf16x4 __attribute__((ext_vector_type(4)));
typedef float f32x4  __attribute__((ext_vector_type(4)));

#define EPS 1e-5f

// ws layout (u16 units): hbg[4096*512] | w2b[55296] | w1b[4096] | fcw1b[65536]
#define HBG_N   (4096 * 512)
#define W2B_OFF HBG_N
#define W1B_OFF (W2B_OFF + 55296)
#define FCW_OFF (W1B_OFF + 4096)

__device__ __forceinline__ u16 f2bf(float f) {
    __hip_bfloat16 h = __float2bfloat16(f);
    return *(const u16*)&h;
}

union BV { bf16x8 v; bf16x4 h[2]; };

// ---- prep: pack weights to bf16 (r9-validated) ----
__global__ __launch_bounds__(256) void prep_kernel(
        const float* __restrict__ W2, const float* __restrict__ W1,
        const float* __restrict__ fcw1, u16* __restrict__ ws) {
    int i = blockIdx.x * 256 + threadIdx.x;
    if (i < 55296) {           // w2b [tap][cout][ci]
        int tap = i >> 11, rem = i & 2047;
        int co = rem >> 5, ci = rem & 31;
        ws[W2B_OFF + i] = f2bf(W2[(size_t)tap * 2048 + ci * 64 + co]);
    }
    if (i < 4096) {            // w1b [ks][quad][cout][8]; tap>=27 zero
        int j = i & 7, cout = (i >> 3) & 31, quad = (i >> 8) & 3, ks = i >> 10;
        int tap = ks * 8 + quad * 2 + (j >> 2), ci = j & 3;
        ws[W1B_OFF + i] = (tap < 27) ? f2bf(W1[tap * 128 + ci * 32 + cout]) : (u16)0;
    }
    if (i < 65536)             // fcw1b [j][k]
        ws[FCW_OFF + i] = f2bf(fcw1[i]);
}

// ---- conv kernel: one block per item, 8 waves (512 threads) ----
// 8-wave split to fix latency-bound regime (occupancy was 28.8% at 4 waves/block):
//   conv1: waves (pz, half) each do 4 of the 8 pool offsets (dz = half);
//          half=0 stores partial pmax to act, half=1 max-combines after barrier.
//   conv2: waves (cout-tile, half) each do a z-pair g = {2*half, 2*half+1}.
// Zero-halo padded LDS volumes kill all boundary VALU (as before).
__global__ __launch_bounds__(512) void conv_kernel(
        const float* __restrict__ x,    const u32*  __restrict__ mask,
        const float* __restrict__ g1,   const float* __restrict__ b1,
        const float* __restrict__ m1,   const float* __restrict__ v1,
        const float* __restrict__ g2,   const float* __restrict__ b2,
        const float* __restrict__ m2,   const float* __restrict__ v2,
        u16* __restrict__ ws) {

    const u16* w2b = ws + W2B_OFF;
    const u16* w1b = ws + W1B_OFF;

    __shared__ __align__(16) u16 xb[1000 * 4];    // padded 10x10x10, [row][ci(4)]
    __shared__ int   msk[512];
    __shared__ __align__(16) u16 act[216 * 40];   // padded 6x6x6, [row][ci(32)+pad]
    __shared__ float mf2s[64];
    __shared__ float h2f[512];                    // [cout][pp] pooled conv2 (f32)
    __shared__ float sc1s[32], sh1s[32], sc2s[64], sh2s[64];

    const int b = blockIdx.x;
    const int t = threadIdx.x;

    // ---- phase 0: BN fold + zero padded volumes ----
    if (t < 32) {
        float sc = g1[t] / sqrtf(v1[t] + EPS);
        sc1s[t] = sc; sh1s[t] = b1[t] - m1[t] * sc;
    } else if (t < 96) {
        int c = t - 32;
        float sc = g2[c] / sqrtf(v2[c] + EPS);
        sc2s[c] = sc; sh2s[c] = b2[c] - m2[c] * sc;
    }
    for (int i = t; i < 2000; i += 512) ((u32*)xb)[i]  = 0u;
    for (int i = t; i < 4320; i += 512) ((u32*)act)[i] = 0u;
    __syncthreads();

    // ---- phase 1: stage x -> padded xb; mask (one shot, 512 threads) ----
    {
        const float* xp = x + (size_t)b * 2048;
        const u32*   mp = mask + (size_t)b * 512;
        const int s = t;
        float a0 = xp[s], a1 = xp[512 + s], a2 = xp[1024 + s], a3 = xp[1536 + s];
        int z = s >> 6, y = (s >> 3) & 7, xx = s & 7;
        int row = z * 100 + y * 10 + xx + 111;   // (z+1,y+1,x+1)
        ((u32*)xb)[row * 2]     = (u32)f2bf(a0) | ((u32)f2bf(a1) << 16);
        ((u32*)xb)[row * 2 + 1] = (u32)f2bf(a2) | ((u32)f2bf(a3) << 16);
        msk[s] = (mp[s] != 0u);
    }
    __syncthreads();

    const int lane = t & 63;
    const int n    = lane & 15;
    const int quad = lane >> 4;
    const int w8   = __builtin_amdgcn_readfirstlane(t >> 6);   // 0..7
    const int pz   = w8 & 3;
    const int half = w8 >> 2;

    // ---- phase 2: conv1(4->32) MFMA + split 2x2x2 maxpool (dz = half) ----
    {
        bf16x8 afr[4][2];
        #pragma unroll
        for (int ks = 0; ks < 4; ++ks)
            #pragma unroll
            for (int mt = 0; mt < 2; ++mt)
                afr[ks][mt] = *(const bf16x8*)(w1b +
                    (((ks * 4 + quad) * 32) + mt * 16 + n) * 8);

        // per-lane padded tap offsets (clamped for tap>=27: A-frag is zero there)
        int dA[8];
        #pragma unroll
        for (int q = 0; q < 8; ++q) {
            int tap = (q >> 1) * 8 + quad * 2 + (q & 1);
            int tc = (tap < 27) ? tap : 26;
            int kd = tc / 9, rr = tc - kd * 9, kh = rr / 3, kw = rr - kh * 3;
            dA[q] = (kd - 1) * 100 + (kh - 1) * 10 + (kw - 1);
        }

        const int py_ = n >> 2, px_ = n & 3;   // pooled coords
        const int zc  = 2 * pz + half;         // this wave's z slice
        float pmax[8];
        #pragma unroll
        for (int j = 0; j < 8; ++j) pmax[j] = 0.f;

        #pragma unroll
        for (int i4 = 0; i4 < 4; ++i4) {       // (dy,dx) pool offsets
            const int y  = 2 * py_ + (i4 >> 1);
            const int xx = 2 * px_ + (i4 & 1);
            const int sPad = zc * 100 + y * 10 + xx + 111;

            f32x4 acc0 = (f32x4){0.f, 0.f, 0.f, 0.f};
            f32x4 acc1 = (f32x4){0.f, 0.f, 0.f, 0.f};

            #pragma unroll
            for (int ks = 0; ks < 4; ++ks) {
                BV bv;
                bv.h[0] = *(const bf16x4*)(xb + (sPad + dA[ks * 2])     * 4);
                bv.h[1] = *(const bf16x4*)(xb + (sPad + dA[ks * 2 + 1]) * 4);
                acc0 = __builtin_amdgcn_mfma_f32_16x16x32_bf16(afr[ks][0], bv.v, acc0, 0, 0, 0);
                acc1 = __builtin_amdgcn_mfma_f32_16x16x32_bf16(afr[ks][1], bv.v, acc1, 0, 0, 0);
            }

            const float mk = msk[zc * 64 + y * 8 + xx] ? 1.f : 0.f;
            #pragma unroll
            for (int r = 0; r < 4; ++r) {
                int c0 = quad * 4 + r, c1 = 16 + quad * 4 + r;
                pmax[r]     = fmaxf(pmax[r],     fmaxf(acc0[r] * sc1s[c0] + sh1s[c0], 0.f) * mk);
                pmax[4 + r] = fmaxf(pmax[4 + r], fmaxf(acc1[r] * sc1s[c1] + sh1s[c1], 0.f) * mk);
            }
        }

        const int prow = (pz + 1) * 36 + (py_ + 1) * 6 + (px_ + 1);

        // half 0: write partial pooled bf16 into padded act row
        if (half == 0) {
            #pragma unroll
            for (int mt = 0; mt < 2; ++mt) {
                u32 lo = (u32)f2bf(pmax[mt * 4])     | ((u32)f2bf(pmax[mt * 4 + 1]) << 16);
                u32 hi = (u32)f2bf(pmax[mt * 4 + 2]) | ((u32)f2bf(pmax[mt * 4 + 3]) << 16);
                ((u32*)act)[prow * 20 + mt * 8 + quad * 2]     = lo;
                ((u32*)act)[prow * 20 + mt * 8 + quad * 2 + 1] = hi;
            }
        }
        __syncthreads();   // barrier A: partials visible

        // half 1: max-combine into act. wave 0 (idle here) computes mf2s from msk.
        if (half == 1) {
            #pragma unroll
            for (int mt = 0; mt < 2; ++mt) {
                u32* p = ((u32*)act) + prow * 20 + mt * 8 + quad * 2;
                u32 w0 = p[0], w1 = p[1];
                float f0 = __uint_as_float(w0 << 16);
                float f1 = __uint_as_float(w0 & 0xffff0000u);
                float f2 = __uint_as_float(w1 << 16);
                float f3 = __uint_as_float(w1 & 0xffff0000u);
                f0 = fmaxf(f0, pmax[mt * 4 + 0]);
                f1 = fmaxf(f1, pmax[mt * 4 + 1]);
                f2 = fmaxf(f2, pmax[mt * 4 + 2]);
                f3 = fmaxf(f3, pmax[mt * 4 + 3]);
                p[0] = (u32)f2bf(f0) | ((u32)f2bf(f1) << 16);
                p[1] = (u32)f2bf(f2) | ((u32)f2bf(f3) << 16);
            }
        }
        if (t < 64) {   // pooled-mask from msk (independent of conv results)
            const int mz = t >> 4, my = (t >> 2) & 3, mx = t & 3;
            int m = 0;
            #pragma unroll
            for (int dz = 0; dz < 2; ++dz)
                #pragma unroll
                for (int dy = 0; dy < 2; ++dy)
                    #pragma unroll
                    for (int dx = 0; dx < 2; ++dx)
                        m |= msk[(2 * mz + dz) * 64 + (2 * my + dy) * 8 + (2 * mx + dx)];
            mf2s[t] = m ? 1.f : 0.f;
        }
    }
    __syncthreads();   // barrier B: combined act + mf2s ready

    // ---- phase 3: conv2(32->64): wave = (cout tile, z-pair) ----
    {
        const int cw   = w8 & 3;
        const int nPad = ((n >> 2) + 1) * 6 + (n & 3) + 1;   // padded (y+1,x+1)
        const int rb0  = nPad + (2 * half) * 36;             // gl=0 row base
        const int rb1  = rb0 + 36;                           // gl=1 row base

        f32x4 acc2[2];
        acc2[0] = (f32x4){0.f, 0.f, 0.f, 0.f};
        acc2[1] = (f32x4){0.f, 0.f, 0.f, 0.f};

        #pragma unroll
        for (int kd = 0; kd < 3; ++kd) {
            #pragma unroll
            for (int kh = 0; kh < 3; ++kh) {
                #pragma unroll
                for (int kw = 0; kw < 3; ++kw) {
                    const int tap = (kd * 3 + kh) * 3 + kw;
                    bf16x8 afrag = *(const bf16x8*)(w2b + tap * 2048 + (cw * 16 + n) * 32 + quad * 8);
                    const int C = kd * 36 + (kh - 1) * 6 + (kw - 1);   // compile-time
                    // gl=0 (g=2*half):   gp=-1 only when half==0,kd==0 -> skip (halo zeros anyway)
                    if (!(kd == 0) || half != 0) {
                        bf16x8 bfrag = *(const bf16x8*)(act + (rb0 + C) * 40 + quad * 8);
                        acc2[0] = __builtin_amdgcn_mfma_f32_16x16x32_bf16(afrag, bfrag, acc2[0], 0, 0, 0);
                    }
                    // gl=1 (g=2*half+1): gp=4 only when half==1,kd==2 -> skip
                    if (!(kd == 2) || half != 1) {
                        bf16x8 bfrag = *(const bf16x8*)(act + (rb1 + C) * 40 + quad * 8);
                        acc2[1] = __builtin_amdgcn_mfma_f32_16x16x32_bf16(afrag, bfrag, acc2[1], 0, 0, 0);
                    }
                }
            }
        }

        // epilogue: BN+ReLU+mask, pool x(shfl1) y(shfl4), z across gl pair
        #pragma unroll
        for (int r = 0; r < 4; ++r) {
            const int cout = cw * 16 + quad * 4 + r;
            float p2g[2];
            #pragma unroll
            for (int gl = 0; gl < 2; ++gl) {
                const int site = (2 * half + gl) * 16 + n;
                float val = fmaxf(acc2[gl][r] * sc2s[cout] + sh2s[cout], 0.f) * mf2s[site];
                float p1 = fmaxf(val, __shfl_xor(val, 1, 64));
                p2g[gl]  = fmaxf(p1,  __shfl_xor(p1, 4, 64));
            }
            if ((n & 5) == 0) {
                const int py = (n >> 3) & 1, px = (n >> 1) & 1;
                h2f[cout * 8 + half * 4 + py * 2 + px] = fmaxf(p2g[0], p2g[1]);
            }
        }
    }
    __syncthreads();

    // ---- phase 4: pack h2f -> hbg bf16 ----
    if (t < 256) {
        u32 pk = (u32)f2bf(h2f[2 * t]) | ((u32)f2bf(h2f[2 * t + 1]) << 16);
        ((u32*)ws)[(size_t)b * 256 + t] = pk;
    }
}

// ---- FC kernel: 256 blocks x 16 items (fills all CUs; mt-tile removed) ----
__global__ __launch_bounds__(256) void fc_kernel(
        const u16* __restrict__ ws,
        const float* __restrict__ fcb1, const float* __restrict__ fcw2,
        const float* __restrict__ fcb2, float* __restrict__ out) {

    const u16* hbg   = ws;
    const u16* fcw1b = ws + FCW_OFF;

    __shared__ __align__(16) u16 abuf[16 * 520];  // [item][k] bf16, padded
    __shared__ float fcpart[16][4];

    const int t = threadIdx.x;
    const int item0 = blockIdx.x * 16;

    {   // stage 16 items x 512 k (bf16), coalesced 64B per thread
        const int it = t >> 4, part = t & 15;
        const uint4* src = (const uint4*)(hbg + (size_t)(item0 + it) * 512 + part * 32);
        uint4* dst = (uint4*)(abuf + it * 520 + part * 32);
        #pragma unroll
        for (int c = 0; c < 4; ++c) dst[c] = src[c];
    }
    __syncthreads();

    const int lane = t & 63;
    const int n    = lane & 15;
    const int quad = lane >> 4;
    const int w    = __builtin_amdgcn_readfirstlane(t >> 6);
    const int jbase = w * 32;

    float fb1[2], fw2[2];
    #pragma unroll
    for (int nt = 0; nt < 2; ++nt) {
        fb1[nt] = fcb1[jbase + nt * 16 + n];
        fw2[nt] = fcw2[jbase + nt * 16 + n];
    }

    f32x4 acc[2];
    acc[0] = (f32x4){0.f, 0.f, 0.f, 0.f};
    acc[1] = (f32x4){0.f, 0.f, 0.f, 0.f};

    #pragma unroll
    for (int ks = 0; ks < 16; ++ks) {
        bf16x8 afr = *(const bf16x8*)(abuf + n * 520 + ks * 32 + quad * 8);
        #pragma unroll
        for (int nt = 0; nt < 2; ++nt) {
            bf16x8 bfr = *(const bf16x8*)(fcw1b + (size_t)(jbase + nt * 16 + n) * 512 + ks * 32 + quad * 8);
            acc[nt] = __builtin_amdgcn_mfma_f32_16x16x32_bf16(afr, bfr, acc[nt], 0, 0, 0);
        }
    }

    #pragma unroll
    for (int r = 0; r < 4; ++r) {
        float s = 0.f;
        #pragma unroll
        for (int nt = 0; nt < 2; ++nt) {
            float y = acc[nt][r] + fb1[nt];
            y = (y >= 0.f) ? y : 0.01f * y;
            s += y * fw2[nt];
        }
        s += __shfl_xor(s, 1, 64);
        s += __shfl_xor(s, 2, 64);
        s += __shfl_xor(s, 4, 64);
        s += __shfl_xor(s, 8, 64);
        if (n == 0) fcpart[quad * 4 + r][w] = s;
    }
    __syncthreads();
    if (t < 16)
        out[item0 + t] = fcpart[t][0] + fcpart[t][1] + fcpart[t][2] + fcpart[t][3] + fcb2[0];
}

extern "C" void kernel_launch(void* const* d_in, const int* in_sizes, int n_in,
                              void* d_out, int out_size, void* d_ws, size_t ws_size,
                              hipStream_t stream) {
    const float* x    = (const float*)d_in[0];
    const u32*   mask = (const u32*)d_in[1];
    const float* W1   = (const float*)d_in[2];
    const float* g1   = (const float*)d_in[3];
    const float* b1   = (const float*)d_in[4];
    const float* m1   = (const float*)d_in[5];
    const float* v1   = (const float*)d_in[6];
    const float* W2   = (const float*)d_in[7];
    const float* g2   = (const float*)d_in[8];
    const float* b2   = (const float*)d_in[9];
    const float* m2   = (const float*)d_in[10];
    const float* v2   = (const float*)d_in[11];
    const float* fcw1 = (const float*)d_in[12];
    const float* fcb1 = (const float*)d_in[13];
    const float* fcw2 = (const float*)d_in[14];
    const float* fcb2 = (const float*)d_in[15];
    u16*   ws  = (u16*)d_ws;
    float* out = (float*)d_out;

    prep_kernel<<<256, 256, 0, stream>>>(W2, W1, fcw1, ws);
    conv_kernel<<<4096, 512, 0, stream>>>(
        x, mask, g1, b1, m1, v1, g2, b2, m2, v2, ws);
    fc_kernel<<<256, 256, 0, stream>>>(ws, fcb1, fcw2, fcb2, out);
}

// Round 2
// 180.963 us; speedup vs baseline: 1.0359x; 1.0359x over previous
//
#include <hip/hip_runtime.h>
#include <hip/hip_bf16.h>

typedef unsigned short u16;
typedef unsigned int   u32;
typedef short bf16x8 __attribute__((ext_vector_type(8)));
typedef short bf16x4 __attribute__((ext_vector_type(4)));
typedef float f32x4  __attribute__((ext_vector_type(4)));

#define EPS 1e-5f

// ws layout (u16 units): hbg[4096*512] | w2b[55296] | w1b[4096] | fcw1b[65536]
#define HBG_N   (4096 * 512)
#define W2B_OFF HBG_N
#define W1B_OFF (W2B_OFF + 55296)
#define FCW_OFF (W1B_OFF + 4096)

__device__ __forceinline__ u16 f2bf(float f) {
    __hip_bfloat16 h = __float2bfloat16(f);
    return *(const u16*)&h;
}

union BV { bf16x8 v; bf16x4 h[2]; };

// ---- prep: pack weights to bf16 (r9-validated) ----
__global__ __launch_bounds__(256) void prep_kernel(
        const float* __restrict__ W2, const float* __restrict__ W1,
        const float* __restrict__ fcw1, u16* __restrict__ ws) {
    int i = blockIdx.x * 256 + threadIdx.x;
    if (i < 55296) {           // w2b [tap][cout][ci]
        int tap = i >> 11, rem = i & 2047;
        int co = rem >> 5, ci = rem & 31;
        ws[W2B_OFF + i] = f2bf(W2[(size_t)tap * 2048 + ci * 64 + co]);
    }
    if (i < 4096) {            // w1b [ks][quad][cout][8]; tap>=27 zero
        int j = i & 7, cout = (i >> 3) & 31, quad = (i >> 8) & 3, ks = i >> 10;
        int tap = ks * 8 + quad * 2 + (j >> 2), ci = j & 3;
        ws[W1B_OFF + i] = (tap < 27) ? f2bf(W1[tap * 128 + ci * 32 + cout]) : (u16)0;
    }
    if (i < 65536)             // fcw1b [j][k]
        ws[FCW_OFF + i] = f2bf(fcw1[i]);
}

// conv2 wave-part: wave = (z-pair G in {0,2}, cout-pair ctp in {0,1}).
// Per (kh,kw): load 3 z-rows of act ONCE into regs, reuse across kd x g x ct.
// bfrag LDS reads: 27/wave (vs 90 in r0) -> LDS pipe is the measured bottleneck.
// All bz indices compile-time (template on G) to avoid scratch spill.
template<int G>
__device__ __forceinline__ void conv2_part(
        const u16* __restrict__ w2b, const u16* act,
        const float* sc2s, const float* sh2s, const float* mf2s, float* h2f,
        int n, int quad, int ctp) {

    const int nPad = ((n >> 2) + 1) * 6 + (n & 3) + 1;   // padded (y+1,x+1)
    constexpr int z0 = (G == 0) ? 1 : 2;                 // lowest padded z-row used

    f32x4 acc[2][2];   // [ct][gl]
    #pragma unroll
    for (int ct = 0; ct < 2; ++ct)
        #pragma unroll
        for (int gl = 0; gl < 2; ++gl) acc[ct][gl] = (f32x4){0.f, 0.f, 0.f, 0.f};

    #pragma unroll
    for (int kh = 0; kh < 3; ++kh) {
        #pragma unroll
        for (int kw = 0; kw < 3; ++kw) {
            bf16x8 bz[3];
            #pragma unroll
            for (int s = 0; s < 3; ++s)
                bz[s] = *(const bf16x8*)(act +
                    (nPad + (z0 + s) * 36 + (kh - 1) * 6 + (kw - 1)) * 40 + quad * 8);
            #pragma unroll
            for (int kd = 0; kd < 3; ++kd) {
                const int tap = (kd * 3 + kh) * 3 + kw;
                bf16x8 af0 = *(const bf16x8*)(w2b + tap * 2048 + ((ctp * 32 +  0) + n) * 32 + quad * 8);
                bf16x8 af1 = *(const bf16x8*)(w2b + tap * 2048 + ((ctp * 32 + 16) + n) * 32 + quad * 8);
                #pragma unroll
                for (int gl = 0; gl < 2; ++gl) {
                    const int zp = G + gl + kd;          // compile-time after unroll
                    if (zp >= 1 && zp <= 4) {
                        acc[0][gl] = __builtin_amdgcn_mfma_f32_16x16x32_bf16(af0, bz[zp - z0], acc[0][gl], 0, 0, 0);
                        acc[1][gl] = __builtin_amdgcn_mfma_f32_16x16x32_bf16(af1, bz[zp - z0], acc[1][gl], 0, 0, 0);
                    }
                }
            }
        }
    }

    // epilogue: BN+ReLU+mask, pool x(shfl1) y(shfl4), z across gl pair
    #pragma unroll
    for (int r = 0; r < 4; ++r) {
        #pragma unroll
        for (int ct = 0; ct < 2; ++ct) {
            const int cout = (ctp * 2 + ct) * 16 + quad * 4 + r;
            float pz2[2];
            #pragma unroll
            for (int gl = 0; gl < 2; ++gl) {
                const int site = (G + gl) * 16 + n;
                float val = fmaxf(acc[ct][gl][r] * sc2s[cout] + sh2s[cout], 0.f) * mf2s[site];
                float p1 = fmaxf(val, __shfl_xor(val, 1, 64));
                pz2[gl]  = fmaxf(p1,  __shfl_xor(p1, 4, 64));
            }
            if ((n & 5) == 0) {
                const int py = (n >> 3) & 1, px = (n >> 1) & 1;
                h2f[cout * 8 + (G >> 1) * 4 + py * 2 + px] = fmaxf(pz2[0], pz2[1]);
            }
        }
    }
}

// ---- conv kernel: one block per item (4096 x 256, 4 waves — r0 structure) ----
__global__ __launch_bounds__(256) void conv_kernel(
        const float* __restrict__ x,    const u32*  __restrict__ mask,
        const float* __restrict__ g1,   const float* __restrict__ b1,
        const float* __restrict__ m1,   const float* __restrict__ v1,
        const float* __restrict__ g2,   const float* __restrict__ b2,
        const float* __restrict__ m2,   const float* __restrict__ v2,
        u16* __restrict__ ws) {

    const u16* w2b = ws + W2B_OFF;
    const u16* w1b = ws + W1B_OFF;

    __shared__ __align__(16) u16 xb[1000 * 4];    // padded 10x10x10, [row][ci(4)]
    __shared__ int   msk[512];
    __shared__ __align__(16) u16 act[216 * 40];   // padded 6x6x6, [row][ci(32)+pad]
    __shared__ float mf2s[64];
    __shared__ float h2f[512];                    // [cout][pp] pooled conv2 (f32)
    __shared__ float sc1s[32], sh1s[32], sc2s[64], sh2s[64];

    const int b = blockIdx.x;
    const int t = threadIdx.x;

    // ---- phase 0: BN fold + zero padded volumes (vectorized b128 stores) ----
    if (t < 32) {
        float sc = g1[t] / sqrtf(v1[t] + EPS);
        sc1s[t] = sc; sh1s[t] = b1[t] - m1[t] * sc;
    } else if (t < 96) {
        int c = t - 32;
        float sc = g2[c] / sqrtf(v2[c] + EPS);
        sc2s[c] = sc; sh2s[c] = b2[c] - m2[c] * sc;
    }
    {
        const uint4 z4 = make_uint4(0u, 0u, 0u, 0u);
        for (int i = t; i < 500;  i += 256) ((uint4*)xb)[i]  = z4;   // 8000 B
        for (int i = t; i < 1080; i += 256) ((uint4*)act)[i] = z4;   // 17280 B
    }
    __syncthreads();

    // ---- phase 1: stage x -> padded xb; mask ----
    {
        const float* xp = x + (size_t)b * 2048;
        const u32*   mp = mask + (size_t)b * 512;
        for (int s = t; s < 512; s += 256) {
            float a0 = xp[s], a1 = xp[512 + s], a2 = xp[1024 + s], a3 = xp[1536 + s];
            int z = s >> 6, y = (s >> 3) & 7, xx = s & 7;
            int row = z * 100 + y * 10 + xx + 111;   // (z+1,y+1,x+1)
            ((u32*)xb)[row * 2]     = (u32)f2bf(a0) | ((u32)f2bf(a1) << 16);
            ((u32*)xb)[row * 2 + 1] = (u32)f2bf(a2) | ((u32)f2bf(a3) << 16);
            msk[s] = (mp[s] != 0u);
        }
    }
    __syncthreads();

    const int lane = t & 63;
    const int n    = lane & 15;
    const int quad = lane >> 4;
    const int w    = __builtin_amdgcn_readfirstlane(t >> 6);

    // ---- phase 2: conv1(4->32) MFMA + in-register 2x2x2 maxpool (r0) ----
    {
        bf16x8 afr[4][2];
        #pragma unroll
        for (int ks = 0; ks < 4; ++ks)
            #pragma unroll
            for (int mt = 0; mt < 2; ++mt)
                afr[ks][mt] = *(const bf16x8*)(w1b +
                    (((ks * 4 + quad) * 32) + mt * 16 + n) * 8);

        // per-lane padded tap offsets (clamped for tap>=27: A-frag is zero there)
        int dA[8];
        #pragma unroll
        for (int q = 0; q < 8; ++q) {
            int tap = (q >> 1) * 8 + quad * 2 + (q & 1);
            int tc = (tap < 27) ? tap : 26;
            int kd = tc / 9, rr = tc - kd * 9, kh = rr / 3, kw = rr - kh * 3;
            dA[q] = (kd - 1) * 100 + (kh - 1) * 10 + (kw - 1);
        }

        const int py_ = n >> 2, px_ = n & 3;   // pooled coords; pz = w
        float pmax[8];
        #pragma unroll
        for (int j = 0; j < 8; ++j) pmax[j] = 0.f;
        int any = 0;

        #pragma unroll
        for (int i = 0; i < 8; ++i) {          // pool offset (dz,dy,dx)
            const int z  = 2 * w   + (i >> 2);
            const int y  = 2 * py_ + ((i >> 1) & 1);
            const int xx = 2 * px_ + (i & 1);
            const int sPad = z * 100 + y * 10 + xx + 111;

            f32x4 acc0 = (f32x4){0.f, 0.f, 0.f, 0.f};
            f32x4 acc1 = (f32x4){0.f, 0.f, 0.f, 0.f};

            #pragma unroll
            for (int ks = 0; ks < 4; ++ks) {
                BV bv;
                bv.h[0] = *(const bf16x4*)(xb + (sPad + dA[ks * 2])     * 4);
                bv.h[1] = *(const bf16x4*)(xb + (sPad + dA[ks * 2 + 1]) * 4);
                acc0 = __builtin_amdgcn_mfma_f32_16x16x32_bf16(afr[ks][0], bv.v, acc0, 0, 0, 0);
                acc1 = __builtin_amdgcn_mfma_f32_16x16x32_bf16(afr[ks][1], bv.v, acc1, 0, 0, 0);
            }

            const int mbit = msk[z * 64 + y * 8 + xx];
            const float mk = mbit ? 1.f : 0.f;
            any |= mbit;
            #pragma unroll
            for (int r = 0; r < 4; ++r) {
                int c0 = quad * 4 + r, c1 = 16 + quad * 4 + r;
                pmax[r]     = fmaxf(pmax[r],     fmaxf(acc0[r] * sc1s[c0] + sh1s[c0], 0.f) * mk);
                pmax[4 + r] = fmaxf(pmax[4 + r], fmaxf(acc1[r] * sc1s[c1] + sh1s[c1], 0.f) * mk);
            }
        }

        // write pooled bf16 into padded act row (w+1, py+1, px+1)
        const int prow = (w + 1) * 36 + (py_ + 1) * 6 + (px_ + 1);
        #pragma unroll
        for (int mt = 0; mt < 2; ++mt) {
            u32 lo = (u32)f2bf(pmax[mt * 4])     | ((u32)f2bf(pmax[mt * 4 + 1]) << 16);
            u32 hi = (u32)f2bf(pmax[mt * 4 + 2]) | ((u32)f2bf(pmax[mt * 4 + 3]) << 16);
            ((u32*)act)[prow * 20 + mt * 8 + quad * 2]     = lo;
            ((u32*)act)[prow * 20 + mt * 8 + quad * 2 + 1] = hi;
        }
        if (quad == 0) mf2s[w * 16 + n] = any ? 1.f : 0.f;
    }
    __syncthreads();

    // ---- phase 3: conv2(32->64): wave = (z-pair, cout-pair); reg-cached bz ----
    {
        const int ctp = w & 1;
        if ((w >> 1) == 0)
            conv2_part<0>(w2b, act, sc2s, sh2s, mf2s, h2f, n, quad, ctp);
        else
            conv2_part<2>(w2b, act, sc2s, sh2s, mf2s, h2f, n, quad, ctp);
    }
    __syncthreads();

    // ---- phase 4: pack h2f -> hbg bf16 ----
    {
        u32 pk = (u32)f2bf(h2f[2 * t]) | ((u32)f2bf(h2f[2 * t + 1]) << 16);
        ((u32*)ws)[(size_t)b * 256 + t] = pk;
    }
}

// ---- FC kernel: 256 blocks x 16 items (fills all CUs) ----
__global__ __launch_bounds__(256) void fc_kernel(
        const u16* __restrict__ ws,
        const float* __restrict__ fcb1, const float* __restrict__ fcw2,
        const float* __restrict__ fcb2, float* __restrict__ out) {

    const u16* hbg   = ws;
    const u16* fcw1b = ws + FCW_OFF;

    __shared__ __align__(16) u16 abuf[16 * 520];  // [item][k] bf16, padded
    __shared__ float fcpart[16][4];

    const int t = threadIdx.x;
    const int item0 = blockIdx.x * 16;

    {   // stage 16 items x 512 k (bf16), coalesced 64B per thread
        const int it = t >> 4, part = t & 15;
        const uint4* src = (const uint4*)(hbg + (size_t)(item0 + it) * 512 + part * 32);
        uint4* dst = (uint4*)(abuf + it * 520 + part * 32);
        #pragma unroll
        for (int c = 0; c < 4; ++c) dst[c] = src[c];
    }
    __syncthreads();

    const int lane = t & 63;
    const int n    = lane & 15;
    const int quad = lane >> 4;
    const int w    = __builtin_amdgcn_readfirstlane(t >> 6);
    const int jbase = w * 32;

    float fb1[2], fw2[2];
    #pragma unroll
    for (int nt = 0; nt < 2; ++nt) {
        fb1[nt] = fcb1[jbase + nt * 16 + n];
        fw2[nt] = fcw2[jbase + nt * 16 + n];
    }

    f32x4 acc[2];
    acc[0] = (f32x4){0.f, 0.f, 0.f, 0.f};
    acc[1] = (f32x4){0.f, 0.f, 0.f, 0.f};

    #pragma unroll
    for (int ks = 0; ks < 16; ++ks) {
        bf16x8 afr = *(const bf16x8*)(abuf + n * 520 + ks * 32 + quad * 8);
        #pragma unroll
        for (int nt = 0; nt < 2; ++nt) {
            bf16x8 bfr = *(const bf16x8*)(fcw1b + (size_t)(jbase + nt * 16 + n) * 512 + ks * 32 + quad * 8);
            acc[nt] = __builtin_amdgcn_mfma_f32_16x16x32_bf16(afr, bfr, acc[nt], 0, 0, 0);
        }
    }

    #pragma unroll
    for (int r = 0; r < 4; ++r) {
        float s = 0.f;
        #pragma unroll
        for (int nt = 0; nt < 2; ++nt) {
            float y = acc[nt][r] + fb1[nt];
            y = (y >= 0.f) ? y : 0.01f * y;
            s += y * fw2[nt];
        }
        s += __shfl_xor(s, 1, 64);
        s += __shfl_xor(s, 2, 64);
        s += __shfl_xor(s, 4, 64);
        s += __shfl_xor(s, 8, 64);
        if (n == 0) fcpart[quad * 4 + r][w] = s;
    }
    __syncthreads();
    if (t < 16)
        out[item0 + t] = fcpart[t][0] + fcpart[t][1] + fcpart[t][2] + fcpart[t][3] + fcb2[0];
}

extern "C" void kernel_launch(void* const* d_in, const int* in_sizes, int n_in,
                              void* d_out, int out_size, void* d_ws, size_t ws_size,
                              hipStream_t stream) {
    const float* x    = (const float*)d_in[0];
    const u32*   mask = (const u32*)d_in[1];
    const float* W1   = (const float*)d_in[2];
    const float* g1   = (const float*)d_in[3];
    const float* b1   = (const float*)d_in[4];
    const float* m1   = (const float*)d_in[5];
    const float* v1   = (const float*)d_in[6];
    const float* W2   = (const float*)d_in[7];
    const float* g2   = (const float*)d_in[8];
    const float* b2   = (const float*)d_in[9];
    const float* m2   = (const float*)d_in[10];
    const float* v2   = (const float*)d_in[11];
    const float* fcw1 = (const float*)d_in[12];
    const float* fcb1 = (const float*)d_in[13];
    const float* fcw2 = (const float*)d_in[14];
    const float* fcb2 = (const float*)d_in[15];
    u16*   ws  = (u16*)d_ws;
    float* out = (float*)d_out;

    prep_kernel<<<256, 256, 0, stream>>>(W2, W1, fcw1, ws);
    conv_kernel<<<4096, 256, 0, stream>>>(
        x, mask, g1, b1, m1, v1, g2, b2, m2, v2, ws);
    fc_kernel<<<256, 256, 0, stream>>>(ws, fcb1, fcw2, fcb2, out);
}

// Round 3
// 160.790 us; speedup vs baseline: 1.1659x; 1.1255x over previous
//
#include <hip/hip_runtime.h>
#include <hip/hip_bf16.h>

typedef unsigned short u16;
typedef unsigned int   u32;
typedef short bf16x8 __attribute__((ext_vector_type(8)));
typedef short bf16x4 __attribute__((ext_vector_type(4)));
typedef float f32x4  __attribute__((ext_vector_type(4)));

#define EPS 1e-5f

// ws layout (u16 units): hbg[4096*512] | w2b[55296] | w1b[4096] | fcw1b[65536]
#define HBG_N   (4096 * 512)
#define W2B_OFF HBG_N
#define W1B_OFF (W2B_OFF + 55296)
#define FCW_OFF (W1B_OFF + 4096)

__device__ __forceinline__ u16 f2bf(float f) {
    __hip_bfloat16 h = __float2bfloat16(f);
    return *(const u16*)&h;
}

union BV { bf16x8 v; bf16x4 h[2]; };

// ---- prep: pack weights to bf16 (r9-validated) ----
__global__ __launch_bounds__(256) void prep_kernel(
        const float* __restrict__ W2, const float* __restrict__ W1,
        const float* __restrict__ fcw1, u16* __restrict__ ws) {
    int i = blockIdx.x * 256 + threadIdx.x;
    if (i < 55296) {           // w2b [tap][cout][ci]
        int tap = i >> 11, rem = i & 2047;
        int co = rem >> 5, ci = rem & 31;
        ws[W2B_OFF + i] = f2bf(W2[(size_t)tap * 2048 + ci * 64 + co]);
    }
    if (i < 4096) {            // w1b [ks][quad][cout][8]; tap>=27 zero
        int j = i & 7, cout = (i >> 3) & 31, quad = (i >> 8) & 3, ks = i >> 10;
        int tap = ks * 8 + quad * 2 + (j >> 2), ci = j & 3;
        ws[W1B_OFF + i] = (tap < 27) ? f2bf(W1[tap * 128 + ci * 32 + cout]) : (u16)0;
    }
    if (i < 65536)             // fcw1b [j][k]
        ws[FCW_OFF + i] = f2bf(fcw1[i]);
}

// ---- conv kernel: one block per item (4096 x 256, 4 waves — r0 structure) ----
// r3: conv2 keeps r0's wave mapping (wave = cout tile, 27 afrag loads each
// feeding 3-4 MFMAs) but hoists the 4 DISTINCT act z-rows per (kh,kw) into
// registers: bfrag LDS reads 90 -> 36 per wave. LDS pipe was the ~75%-busy
// resource (r0 counters); global-load structure untouched (r2's mistake).
__global__ __launch_bounds__(256) void conv_kernel(
        const float* __restrict__ x,    const u32*  __restrict__ mask,
        const float* __restrict__ g1,   const float* __restrict__ b1,
        const float* __restrict__ m1,   const float* __restrict__ v1,
        const float* __restrict__ g2,   const float* __restrict__ b2,
        const float* __restrict__ m2,   const float* __restrict__ v2,
        u16* __restrict__ ws) {

    const u16* w2b = ws + W2B_OFF;
    const u16* w1b = ws + W1B_OFF;

    __shared__ __align__(16) u16 xb[1000 * 4];    // padded 10x10x10, [row][ci(4)]
    __shared__ int   msk[512];
    __shared__ __align__(16) u16 act[216 * 40];   // padded 6x6x6, [row][ci(32)+pad]
    __shared__ float mf2s[64];
    __shared__ float h2f[512];                    // [cout][pp] pooled conv2 (f32)
    __shared__ float sc1s[32], sh1s[32], sc2s[64], sh2s[64];

    const int b = blockIdx.x;
    const int t = threadIdx.x;

    // ---- phase 0: BN fold + zero padded volumes (vectorized b128 stores) ----
    if (t < 32) {
        float sc = g1[t] / sqrtf(v1[t] + EPS);
        sc1s[t] = sc; sh1s[t] = b1[t] - m1[t] * sc;
    } else if (t < 96) {
        int c = t - 32;
        float sc = g2[c] / sqrtf(v2[c] + EPS);
        sc2s[c] = sc; sh2s[c] = b2[c] - m2[c] * sc;
    }
    {
        const uint4 z4 = make_uint4(0u, 0u, 0u, 0u);
        for (int i = t; i < 500;  i += 256) ((uint4*)xb)[i]  = z4;   // 8000 B
        for (int i = t; i < 1080; i += 256) ((uint4*)act)[i] = z4;   // 17280 B
    }
    __syncthreads();

    // ---- phase 1: stage x -> padded xb; mask ----
    {
        const float* xp = x + (size_t)b * 2048;
        const u32*   mp = mask + (size_t)b * 512;
        for (int s = t; s < 512; s += 256) {
            float a0 = xp[s], a1 = xp[512 + s], a2 = xp[1024 + s], a3 = xp[1536 + s];
            int z = s >> 6, y = (s >> 3) & 7, xx = s & 7;
            int row = z * 100 + y * 10 + xx + 111;   // (z+1,y+1,x+1)
            ((u32*)xb)[row * 2]     = (u32)f2bf(a0) | ((u32)f2bf(a1) << 16);
            ((u32*)xb)[row * 2 + 1] = (u32)f2bf(a2) | ((u32)f2bf(a3) << 16);
            msk[s] = (mp[s] != 0u);
        }
    }
    __syncthreads();

    const int lane = t & 63;
    const int n    = lane & 15;
    const int quad = lane >> 4;
    const int w    = __builtin_amdgcn_readfirstlane(t >> 6);

    // ---- phase 2: conv1(4->32) MFMA + in-register 2x2x2 maxpool (r0) ----
    {
        bf16x8 afr[4][2];
        #pragma unroll
        for (int ks = 0; ks < 4; ++ks)
            #pragma unroll
            for (int mt = 0; mt < 2; ++mt)
                afr[ks][mt] = *(const bf16x8*)(w1b +
                    (((ks * 4 + quad) * 32) + mt * 16 + n) * 8);

        // per-lane padded tap offsets (clamped for tap>=27: A-frag is zero there)
        int dA[8];
        #pragma unroll
        for (int q = 0; q < 8; ++q) {
            int tap = (q >> 1) * 8 + quad * 2 + (q & 1);
            int tc = (tap < 27) ? tap : 26;
            int kd = tc / 9, rr = tc - kd * 9, kh = rr / 3, kw = rr - kh * 3;
            dA[q] = (kd - 1) * 100 + (kh - 1) * 10 + (kw - 1);
        }

        const int py_ = n >> 2, px_ = n & 3;   // pooled coords; pz = w
        float pmax[8];
        #pragma unroll
        for (int j = 0; j < 8; ++j) pmax[j] = 0.f;
        int any = 0;

        #pragma unroll
        for (int i = 0; i < 8; ++i) {          // pool offset (dz,dy,dx)
            const int z  = 2 * w   + (i >> 2);
            const int y  = 2 * py_ + ((i >> 1) & 1);
            const int xx = 2 * px_ + (i & 1);
            const int sPad = z * 100 + y * 10 + xx + 111;

            f32x4 acc0 = (f32x4){0.f, 0.f, 0.f, 0.f};
            f32x4 acc1 = (f32x4){0.f, 0.f, 0.f, 0.f};

            #pragma unroll
            for (int ks = 0; ks < 4; ++ks) {
                BV bv;
                bv.h[0] = *(const bf16x4*)(xb + (sPad + dA[ks * 2])     * 4);
                bv.h[1] = *(const bf16x4*)(xb + (sPad + dA[ks * 2 + 1]) * 4);
                acc0 = __builtin_amdgcn_mfma_f32_16x16x32_bf16(afr[ks][0], bv.v, acc0, 0, 0, 0);
                acc1 = __builtin_amdgcn_mfma_f32_16x16x32_bf16(afr[ks][1], bv.v, acc1, 0, 0, 0);
            }

            const int mbit = msk[z * 64 + y * 8 + xx];
            const float mk = mbit ? 1.f : 0.f;
            any |= mbit;
            #pragma unroll
            for (int r = 0; r < 4; ++r) {
                int c0 = quad * 4 + r, c1 = 16 + quad * 4 + r;
                pmax[r]     = fmaxf(pmax[r],     fmaxf(acc0[r] * sc1s[c0] + sh1s[c0], 0.f) * mk);
                pmax[4 + r] = fmaxf(pmax[4 + r], fmaxf(acc1[r] * sc1s[c1] + sh1s[c1], 0.f) * mk);
            }
        }

        // write pooled bf16 into padded act row (w+1, py+1, px+1)
        const int prow = (w + 1) * 36 + (py_ + 1) * 6 + (px_ + 1);
        #pragma unroll
        for (int mt = 0; mt < 2; ++mt) {
            u32 lo = (u32)f2bf(pmax[mt * 4])     | ((u32)f2bf(pmax[mt * 4 + 1]) << 16);
            u32 hi = (u32)f2bf(pmax[mt * 4 + 2]) | ((u32)f2bf(pmax[mt * 4 + 3]) << 16);
            ((u32*)act)[prow * 20 + mt * 8 + quad * 2]     = lo;
            ((u32*)act)[prow * 20 + mt * 8 + quad * 2 + 1] = hi;
        }
        if (quad == 0) mf2s[w * 16 + n] = any ? 1.f : 0.f;
    }
    __syncthreads();

    // ---- phase 3: conv2(32->64): wave = cout tile; reg-cached 4 z-rows ----
    {
        const int nPad = ((n >> 2) + 1) * 6 + (n & 3) + 1;   // padded (y+1,x+1)

        f32x4 acc[4];
        #pragma unroll
        for (int g = 0; g < 4; ++g) acc[g] = (f32x4){0.f, 0.f, 0.f, 0.f};

        #pragma unroll
        for (int kh = 0; kh < 3; ++kh) {
            #pragma unroll
            for (int kw = 0; kw < 3; ++kw) {
                // 4 distinct B-frags (z-planes 1..4) for this (kh,kw), once
                bf16x8 bz[4];
                #pragma unroll
                for (int s = 0; s < 4; ++s)
                    bz[s] = *(const bf16x8*)(act +
                        (nPad + (s + 1) * 36 + (kh - 1) * 6 + (kw - 1)) * 40 + quad * 8);
                #pragma unroll
                for (int kd = 0; kd < 3; ++kd) {
                    const int tap = (kd * 3 + kh) * 3 + kw;
                    bf16x8 afrag = *(const bf16x8*)(w2b + tap * 2048 + (w * 16 + n) * 32 + quad * 8);
                    #pragma unroll
                    for (int g = 0; g < 4; ++g) {
                        const int gp = g + kd - 1;        // compile-time after unroll
                        if (gp < 0 || gp > 3) continue;
                        acc[g] = __builtin_amdgcn_mfma_f32_16x16x32_bf16(
                                     afrag, bz[gp], acc[g], 0, 0, 0);
                    }
                }
            }
        }

        // epilogue: BN+ReLU+mask, pool x(shfl1) y(shfl4), z in registers
        #pragma unroll
        for (int r = 0; r < 4; ++r) {
            const int cout = w * 16 + quad * 4 + r;
            float p2g[4];
            #pragma unroll
            for (int g = 0; g < 4; ++g) {
                const int site = g * 16 + n;
                float val = fmaxf(acc[g][r] * sc2s[cout] + sh2s[cout], 0.f) * mf2s[site];
                float p1 = fmaxf(val, __shfl_xor(val, 1, 64));
                p2g[g]   = fmaxf(p1,  __shfl_xor(p1, 4, 64));
            }
            if ((n & 5) == 0) {
                const int py = (n >> 3) & 1, px = (n >> 1) & 1;
                h2f[cout * 8 + 0 * 4 + py * 2 + px] = fmaxf(p2g[0], p2g[1]);
                h2f[cout * 8 + 1 * 4 + py * 2 + px] = fmaxf(p2g[2], p2g[3]);
            }
        }
    }
    __syncthreads();

    // ---- phase 4: pack h2f -> hbg bf16 ----
    {
        u32 pk = (u32)f2bf(h2f[2 * t]) | ((u32)f2bf(h2f[2 * t + 1]) << 16);
        ((u32*)ws)[(size_t)b * 256 + t] = pk;
    }
}

// ---- FC kernel: 256 blocks x 16 items (fills all CUs) ----
__global__ __launch_bounds__(256) void fc_kernel(
        const u16* __restrict__ ws,
        const float* __restrict__ fcb1, const float* __restrict__ fcw2,
        const float* __restrict__ fcb2, float* __restrict__ out) {

    const u16* hbg   = ws;
    const u16* fcw1b = ws + FCW_OFF;

    __shared__ __align__(16) u16 abuf[16 * 520];  // [item][k] bf16, padded
    __shared__ float fcpart[16][4];

    const int t = threadIdx.x;
    const int item0 = blockIdx.x * 16;

    {   // stage 16 items x 512 k (bf16), coalesced 64B per thread
        const int it = t >> 4, part = t & 15;
        const uint4* src = (const uint4*)(hbg + (size_t)(item0 + it) * 512 + part * 32);
        uint4* dst = (uint4*)(abuf + it * 520 + part * 32);
        #pragma unroll
        for (int c = 0; c < 4; ++c) dst[c] = src[c];
    }
    __syncthreads();

    const int lane = t & 63;
    const int n    = lane & 15;
    const int quad = lane >> 4;
    const int w    = __builtin_amdgcn_readfirstlane(t >> 6);
    const int jbase = w * 32;

    float fb1[2], fw2[2];
    #pragma unroll
    for (int nt = 0; nt < 2; ++nt) {
        fb1[nt] = fcb1[jbase + nt * 16 + n];
        fw2[nt] = fcw2[jbase + nt * 16 + n];
    }

    f32x4 acc[2];
    acc[0] = (f32x4){0.f, 0.f, 0.f, 0.f};
    acc[1] = (f32x4){0.f, 0.f, 0.f, 0.f};

    #pragma unroll
    for (int ks = 0; ks < 16; ++ks) {
        bf16x8 afr = *(const bf16x8*)(abuf + n * 520 + ks * 32 + quad * 8);
        #pragma unroll
        for (int nt = 0; nt < 2; ++nt) {
            bf16x8 bfr = *(const bf16x8*)(fcw1b + (size_t)(jbase + nt * 16 + n) * 512 + ks * 32 + quad * 8);
            acc[nt] = __builtin_amdgcn_mfma_f32_16x16x32_bf16(afr, bfr, acc[nt], 0, 0, 0);
        }
    }

    #pragma unroll
    for (int r = 0; r < 4; ++r) {
        float s = 0.f;
        #pragma unroll
        for (int nt = 0; nt < 2; ++nt) {
            float y = acc[nt][r] + fb1[nt];
            y = (y >= 0.f) ? y : 0.01f * y;
            s += y * fw2[nt];
        }
        s += __shfl_xor(s, 1, 64);
        s += __shfl_xor(s, 2, 64);
        s += __shfl_xor(s, 4, 64);
        s += __shfl_xor(s, 8, 64);
        if (n == 0) fcpart[quad * 4 + r][w] = s;
    }
    __syncthreads();
    if (t < 16)
        out[item0 + t] = fcpart[t][0] + fcpart[t][1] + fcpart[t][2] + fcpart[t][3] + fcb2[0];
}

extern "C" void kernel_launch(void* const* d_in, const int* in_sizes, int n_in,
                              void* d_out, int out_size, void* d_ws, size_t ws_size,
                              hipStream_t stream) {
    const float* x    = (const float*)d_in[0];
    const u32*   mask = (const u32*)d_in[1];
    const float* W1   = (const float*)d_in[2];
    const float* g1   = (const float*)d_in[3];
    const float* b1   = (const float*)d_in[4];
    const float* m1   = (const float*)d_in[5];
    const float* v1   = (const float*)d_in[6];
    const float* W2   = (const float*)d_in[7];
    const float* g2   = (const float*)d_in[8];
    const float* b2   = (const float*)d_in[9];
    const float* m2   = (const float*)d_in[10];
    const float* v2   = (const float*)d_in[11];
    const float* fcw1 = (const float*)d_in[12];
    const float* fcb1 = (const float*)d_in[13];
    const float* fcw2 = (const float*)d_in[14];
    const float* fcb2 = (const float*)d_in[15];
    u16*   ws  = (u16*)d_ws;
    float* out = (float*)d_out;

    prep_kernel<<<256, 256, 0, stream>>>(W2, W1, fcw1, ws);
    conv_kernel<<<4096, 256, 0, stream>>>(
        x, mask, g1, b1, m1, v1, g2, b2, m2, v2, ws);
    fc_kernel<<<256, 256, 0, stream>>>(ws, fcb1, fcw2, fcb2, out);
}

// Round 4
// 158.835 us; speedup vs baseline: 1.1802x; 1.0123x over previous
//
#include <hip/hip_runtime.h>
#include <hip/hip_bf16.h>

typedef unsigned short u16;
typedef unsigned int   u32;
typedef short bf16x8 __attribute__((ext_vector_type(8)));
typedef short bf16x4 __attribute__((ext_vector_type(4)));
typedef float f32x4  __attribute__((ext_vector_type(4)));

#define EPS 1e-5f

// ws layout (u16 units): hbg[4096*512] | w2b[55296] | w1b[4096] | fcw1b[65536]
#define HBG_N   (4096 * 512)
#define W2B_OFF HBG_N
#define W1B_OFF (W2B_OFF + 55296)
#define FCW_OFF (W1B_OFF + 4096)

__device__ __forceinline__ u16 f2bf(float f) {
    __hip_bfloat16 h = __float2bfloat16(f);
    return *(const u16*)&h;
}

union BV { bf16x8 v; bf16x4 h[2]; };

// ---- prep: pack weights to bf16 (r9-validated) ----
__global__ __launch_bounds__(256) void prep_kernel(
        const float* __restrict__ W2, const float* __restrict__ W1,
        const float* __restrict__ fcw1, u16* __restrict__ ws) {
    int i = blockIdx.x * 256 + threadIdx.x;
    if (i < 55296) {           // w2b [tap][cout][ci]
        int tap = i >> 11, rem = i & 2047;
        int co = rem >> 5, ci = rem & 31;
        ws[W2B_OFF + i] = f2bf(W2[(size_t)tap * 2048 + ci * 64 + co]);
    }
    if (i < 4096) {            // w1b [ks][quad][cout][8]; tap>=27 zero
        int j = i & 7, cout = (i >> 3) & 31, quad = (i >> 8) & 3, ks = i >> 10;
        int tap = ks * 8 + quad * 2 + (j >> 2), ci = j & 3;
        ws[W1B_OFF + i] = (tap < 27) ? f2bf(W1[tap * 128 + ci * 32 + cout]) : (u16)0;
    }
    if (i < 65536)             // fcw1b [j][k]
        ws[FCW_OFF + i] = f2bf(fcw1[i]);
}

// ---- conv kernel: TWO items per block (2048 x 512, 8 waves) ----
// r4: latency-bound diagnosis (r3: no pipe >50%, occupancy 28.8% = 2.3
// blocks/CU). Waves 0-3 run item A, waves 4-7 item B — per-wave code is
// r3 verbatim on a private LDS copy. 58.6 KB LDS -> 2 blocks/CU = 16
// waves/CU. Per-CU op totals unchanged; only residency/overlap improves.
__global__ __launch_bounds__(512) void conv_kernel(
        const float* __restrict__ x,    const u32*  __restrict__ mask,
        const float* __restrict__ g1,   const float* __restrict__ b1,
        const float* __restrict__ m1,   const float* __restrict__ v1,
        const float* __restrict__ g2,   const float* __restrict__ b2,
        const float* __restrict__ m2,   const float* __restrict__ v2,
        u16* __restrict__ ws) {

    const u16* w2b = ws + W2B_OFF;
    const u16* w1b = ws + W1B_OFF;

    __shared__ __align__(16) u16 xb[2][1000 * 4];   // padded 10x10x10, [row][ci(4)]
    __shared__ int   msk[2][512];
    __shared__ __align__(16) u16 act[2][216 * 40];  // padded 6x6x6, [row][ci(32)+pad]
    __shared__ float mf2s[2][64];
    __shared__ float h2f[2][512];                   // [cout][pp] pooled conv2 (f32)
    __shared__ float sc1s[32], sh1s[32], sc2s[64], sh2s[64];

    const int b2i = blockIdx.x * 2;
    const int t   = threadIdx.x;

    // ---- phase 0: BN fold + zero padded volumes (vectorized b128 stores) ----
    if (t < 32) {
        float sc = g1[t] / sqrtf(v1[t] + EPS);
        sc1s[t] = sc; sh1s[t] = b1[t] - m1[t] * sc;
    } else if (t < 96) {
        int c = t - 32;
        float sc = g2[c] / sqrtf(v2[c] + EPS);
        sc2s[c] = sc; sh2s[c] = b2[c] - m2[c] * sc;
    }
    {
        const uint4 z4 = make_uint4(0u, 0u, 0u, 0u);
        for (int i = t; i < 1000; i += 512) ((uint4*)xb)[i]  = z4;   // 16000 B
        for (int i = t; i < 2160; i += 512) ((uint4*)act)[i] = z4;   // 34560 B
    }
    __syncthreads();

    // ---- phase 1: stage x -> padded xb; mask (both items) ----
    {
        #pragma unroll
        for (int rep = 0; rep < 2; ++rep) {
            const int sl = t + rep * 512;        // 0..1023
            const int it = sl >> 9, s = sl & 511;
            const float* xp = x + (size_t)(b2i + it) * 2048;
            const u32*   mp = mask + (size_t)(b2i + it) * 512;
            float a0 = xp[s], a1 = xp[512 + s], a2 = xp[1024 + s], a3 = xp[1536 + s];
            int z = s >> 6, y = (s >> 3) & 7, xx = s & 7;
            int row = z * 100 + y * 10 + xx + 111;   // (z+1,y+1,x+1)
            ((u32*)(xb[it]))[row * 2]     = (u32)f2bf(a0) | ((u32)f2bf(a1) << 16);
            ((u32*)(xb[it]))[row * 2 + 1] = (u32)f2bf(a2) | ((u32)f2bf(a3) << 16);
            msk[it][s] = (mp[s] != 0u);
        }
    }
    __syncthreads();

    const int lane = t & 63;
    const int n    = lane & 15;
    const int quad = lane >> 4;
    const int w8   = __builtin_amdgcn_readfirstlane(t >> 6);
    const int it   = w8 >> 2;        // item within block
    const int w    = w8 & 3;         // r3's wave role
    const u16* xbI  = xb[it];
    const int* mskI = msk[it];
    u16* actI = act[it];

    // ---- phase 2: conv1(4->32) MFMA + in-register 2x2x2 maxpool (r3) ----
    {
        bf16x8 afr[4][2];
        #pragma unroll
        for (int ks = 0; ks < 4; ++ks)
            #pragma unroll
            for (int mt = 0; mt < 2; ++mt)
                afr[ks][mt] = *(const bf16x8*)(w1b +
                    (((ks * 4 + quad) * 32) + mt * 16 + n) * 8);

        // per-lane padded tap offsets (clamped for tap>=27: A-frag is zero there)
        int dA[8];
        #pragma unroll
        for (int q = 0; q < 8; ++q) {
            int tap = (q >> 1) * 8 + quad * 2 + (q & 1);
            int tc = (tap < 27) ? tap : 26;
            int kd = tc / 9, rr = tc - kd * 9, kh = rr / 3, kw = rr - kh * 3;
            dA[q] = (kd - 1) * 100 + (kh - 1) * 10 + (kw - 1);
        }

        const int py_ = n >> 2, px_ = n & 3;   // pooled coords; pz = w
        float pmax[8];
        #pragma unroll
        for (int j = 0; j < 8; ++j) pmax[j] = 0.f;
        int any = 0;

        #pragma unroll
        for (int i = 0; i < 8; ++i) {          // pool offset (dz,dy,dx)
            const int z  = 2 * w   + (i >> 2);
            const int y  = 2 * py_ + ((i >> 1) & 1);
            const int xx = 2 * px_ + (i & 1);
            const int sPad = z * 100 + y * 10 + xx + 111;

            f32x4 acc0 = (f32x4){0.f, 0.f, 0.f, 0.f};
            f32x4 acc1 = (f32x4){0.f, 0.f, 0.f, 0.f};

            #pragma unroll
            for (int ks = 0; ks < 4; ++ks) {
                BV bv;
                bv.h[0] = *(const bf16x4*)(xbI + (sPad + dA[ks * 2])     * 4);
                bv.h[1] = *(const bf16x4*)(xbI + (sPad + dA[ks * 2 + 1]) * 4);
                acc0 = __builtin_amdgcn_mfma_f32_16x16x32_bf16(afr[ks][0], bv.v, acc0, 0, 0, 0);
                acc1 = __builtin_amdgcn_mfma_f32_16x16x32_bf16(afr[ks][1], bv.v, acc1, 0, 0, 0);
            }

            const int mbit = mskI[z * 64 + y * 8 + xx];
            const float mk = mbit ? 1.f : 0.f;
            any |= mbit;
            #pragma unroll
            for (int r = 0; r < 4; ++r) {
                int c0 = quad * 4 + r, c1 = 16 + quad * 4 + r;
                pmax[r]     = fmaxf(pmax[r],     fmaxf(acc0[r] * sc1s[c0] + sh1s[c0], 0.f) * mk);
                pmax[4 + r] = fmaxf(pmax[4 + r], fmaxf(acc1[r] * sc1s[c1] + sh1s[c1], 0.f) * mk);
            }
        }

        // write pooled bf16 into padded act row (w+1, py+1, px+1)
        const int prow = (w + 1) * 36 + (py_ + 1) * 6 + (px_ + 1);
        #pragma unroll
        for (int mt = 0; mt < 2; ++mt) {
            u32 lo = (u32)f2bf(pmax[mt * 4])     | ((u32)f2bf(pmax[mt * 4 + 1]) << 16);
            u32 hi = (u32)f2bf(pmax[mt * 4 + 2]) | ((u32)f2bf(pmax[mt * 4 + 3]) << 16);
            ((u32*)actI)[prow * 20 + mt * 8 + quad * 2]     = lo;
            ((u32*)actI)[prow * 20 + mt * 8 + quad * 2 + 1] = hi;
        }
        if (quad == 0) mf2s[it][w * 16 + n] = any ? 1.f : 0.f;
    }
    __syncthreads();

    // ---- phase 3: conv2(32->64): wave = cout tile; reg-cached 4 z-rows ----
    {
        const int nPad = ((n >> 2) + 1) * 6 + (n & 3) + 1;   // padded (y+1,x+1)

        f32x4 acc[4];
        #pragma unroll
        for (int g = 0; g < 4; ++g) acc[g] = (f32x4){0.f, 0.f, 0.f, 0.f};

        #pragma unroll
        for (int kh = 0; kh < 3; ++kh) {
            #pragma unroll
            for (int kw = 0; kw < 3; ++kw) {
                // 4 distinct B-frags (z-planes 1..4) for this (kh,kw), once
                bf16x8 bz[4];
                #pragma unroll
                for (int s = 0; s < 4; ++s)
                    bz[s] = *(const bf16x8*)(actI +
                        (nPad + (s + 1) * 36 + (kh - 1) * 6 + (kw - 1)) * 40 + quad * 8);
                #pragma unroll
                for (int kd = 0; kd < 3; ++kd) {
                    const int tap = (kd * 3 + kh) * 3 + kw;
                    bf16x8 afrag = *(const bf16x8*)(w2b + tap * 2048 + (w * 16 + n) * 32 + quad * 8);
                    #pragma unroll
                    for (int g = 0; g < 4; ++g) {
                        const int gp = g + kd - 1;        // compile-time after unroll
                        if (gp < 0 || gp > 3) continue;
                        acc[g] = __builtin_amdgcn_mfma_f32_16x16x32_bf16(
                                     afrag, bz[gp], acc[g], 0, 0, 0);
                    }
                }
            }
        }

        // epilogue: BN+ReLU+mask, pool x(shfl1) y(shfl4), z in registers
        #pragma unroll
        for (int r = 0; r < 4; ++r) {
            const int cout = w * 16 + quad * 4 + r;
            float p2g[4];
            #pragma unroll
            for (int g = 0; g < 4; ++g) {
                const int site = g * 16 + n;
                float val = fmaxf(acc[g][r] * sc2s[cout] + sh2s[cout], 0.f) * mf2s[it][site];
                float p1 = fmaxf(val, __shfl_xor(val, 1, 64));
                p2g[g]   = fmaxf(p1,  __shfl_xor(p1, 4, 64));
            }
            if ((n & 5) == 0) {
                const int py = (n >> 3) & 1, px = (n >> 1) & 1;
                h2f[it][cout * 8 + 0 * 4 + py * 2 + px] = fmaxf(p2g[0], p2g[1]);
                h2f[it][cout * 8 + 1 * 4 + py * 2 + px] = fmaxf(p2g[2], p2g[3]);
            }
        }
    }
    __syncthreads();

    // ---- phase 4: pack h2f -> hbg bf16 (both items) ----
    {
        const int pit = t >> 8, j = t & 255;
        u32 pk = (u32)f2bf(h2f[pit][2 * j]) | ((u32)f2bf(h2f[pit][2 * j + 1]) << 16);
        ((u32*)ws)[(size_t)(b2i + pit) * 256 + j] = pk;
    }
}

// ---- FC kernel: 256 blocks x 16 items (fills all CUs) ----
__global__ __launch_bounds__(256) void fc_kernel(
        const u16* __restrict__ ws,
        const float* __restrict__ fcb1, const float* __restrict__ fcw2,
        const float* __restrict__ fcb2, float* __restrict__ out) {

    const u16* hbg   = ws;
    const u16* fcw1b = ws + FCW_OFF;

    __shared__ __align__(16) u16 abuf[16 * 520];  // [item][k] bf16, padded
    __shared__ float fcpart[16][4];

    const int t = threadIdx.x;
    const int item0 = blockIdx.x * 16;

    {   // stage 16 items x 512 k (bf16), coalesced 64B per thread
        const int it = t >> 4, part = t & 15;
        const uint4* src = (const uint4*)(hbg + (size_t)(item0 + it) * 512 + part * 32);
        uint4* dst = (uint4*)(abuf + it * 520 + part * 32);
        #pragma unroll
        for (int c = 0; c < 4; ++c) dst[c] = src[c];
    }
    __syncthreads();

    const int lane = t & 63;
    const int n    = lane & 15;
    const int quad = lane >> 4;
    const int w    = __builtin_amdgcn_readfirstlane(t >> 6);
    const int jbase = w * 32;

    float fb1[2], fw2[2];
    #pragma unroll
    for (int nt = 0; nt < 2; ++nt) {
        fb1[nt] = fcb1[jbase + nt * 16 + n];
        fw2[nt] = fcw2[jbase + nt * 16 + n];
    }

    f32x4 acc[2];
    acc[0] = (f32x4){0.f, 0.f, 0.f, 0.f};
    acc[1] = (f32x4){0.f, 0.f, 0.f, 0.f};

    #pragma unroll
    for (int ks = 0; ks < 16; ++ks) {
        bf16x8 afr = *(const bf16x8*)(abuf + n * 520 + ks * 32 + quad * 8);
        #pragma unroll
        for (int nt = 0; nt < 2; ++nt) {
            bf16x8 bfr = *(const bf16x8*)(fcw1b + (size_t)(jbase + nt * 16 + n) * 512 + ks * 32 + quad * 8);
            acc[nt] = __builtin_amdgcn_mfma_f32_16x16x32_bf16(afr, bfr, acc[nt], 0, 0, 0);
        }
    }

    #pragma unroll
    for (int r = 0; r < 4; ++r) {
        float s = 0.f;
        #pragma unroll
        for (int nt = 0; nt < 2; ++nt) {
            float y = acc[nt][r] + fb1[nt];
            y = (y >= 0.f) ? y : 0.01f * y;
            s += y * fw2[nt];
        }
        s += __shfl_xor(s, 1, 64);
        s += __shfl_xor(s, 2, 64);
        s += __shfl_xor(s, 4, 64);
        s += __shfl_xor(s, 8, 64);
        if (n == 0) fcpart[quad * 4 + r][w] = s;
    }
    __syncthreads();
    if (t < 16)
        out[item0 + t] = fcpart[t][0] + fcpart[t][1] + fcpart[t][2] + fcpart[t][3] + fcb2[0];
}

extern "C" void kernel_launch(void* const* d_in, const int* in_sizes, int n_in,
                              void* d_out, int out_size, void* d_ws, size_t ws_size,
                              hipStream_t stream) {
    const float* x    = (const float*)d_in[0];
    const u32*   mask = (const u32*)d_in[1];
    const float* W1   = (const float*)d_in[2];
    const float* g1   = (const float*)d_in[3];
    const float* b1   = (const float*)d_in[4];
    const float* m1   = (const float*)d_in[5];
    const float* v1   = (const float*)d_in[6];
    const float* W2   = (const float*)d_in[7];
    const float* g2   = (const float*)d_in[8];
    const float* b2   = (const float*)d_in[9];
    const float* m2   = (const float*)d_in[10];
    const float* v2   = (const float*)d_in[11];
    const float* fcw1 = (const float*)d_in[12];
    const float* fcb1 = (const float*)d_in[13];
    const float* fcw2 = (const float*)d_in[14];
    const float* fcb2 = (const float*)d_in[15];
    u16*   ws  = (u16*)d_ws;
    float* out = (float*)d_out;

    prep_kernel<<<256, 256, 0, stream>>>(W2, W1, fcw1, ws);
    conv_kernel<<<2048, 512, 0, stream>>>(
        x, mask, g1, b1, m1, v1, g2, b2, m2, v2, ws);
    fc_kernel<<<256, 256, 0, stream>>>(ws, fcb1, fcw2, fcb2, out);
}